// Round 20
// baseline (233.873 us; speedup 1.0000x reference)
//
#include <hip/hip_runtime.h>
#include <hip/hip_bf16.h>

// NCA update, round 20: barrier-free wave-autonomous tiles. Each wave owns
// one 16-px tile end-to-end (filter 16ch x 16px -> per-wave Y LDS -> GEMM1
// all 8 M-tiles -> per-wave H LDS -> GEMM2 -> epilogue). Zero __syncthreads.
// A1 preloaded (16 frags) so the mt loop is pure ds_read+MFMA (fixes R15's
// serial-VMEM failure). Per-px math bit-identical to R19.

#define CCH 16
#define HID 128
#define HH 256
#define WW 256
#define BB 32

typedef __attribute__((ext_vector_type(8))) short bf16x8;
typedef __attribute__((ext_vector_type(4))) float f32x4;
typedef __attribute__((ext_vector_type(4))) int i32x4;
typedef __attribute__((ext_vector_type(2))) unsigned int u32x2;

union bfpack {
  u32x2 w2[2];
  bf16x8 v;
};

__device__ inline unsigned short f2bf(float f) {  // RNE
  unsigned int u = __float_as_uint(f);
  u += 0x7FFFu + ((u >> 16) & 1u);
  return (unsigned short)(u >> 16);
}
__device__ inline unsigned int cvtpk2(float a, float b) {  // v_cvt_pk_bf16_f32
  union { __hip_bfloat162 h; unsigned int u; } cv;
  cv.h = __float22bfloat162_rn(make_float2(a, b));
  return cv.u;
}

// ---------------------------------------------------------------- prep
// w1p[((ks*8 + mt)*64 + lane)*8 + j]; row = mt*16+(l&15),
// k'' = ks*32+(l>>4)*8+j; k''=c*4+f -> w1[row][c*3+f]; k''==3 -> b1[row]
// (bias column, pairs with Y[3]=1.0 at c==0); other f==3 -> 0. bf16 (hi only).
// w2p[(ks*64 + lane)*8 + j]; out-ch = l&15, k = ks*32+(l>>4)*8+j. bf16.
__global__ __launch_bounds__(256) void pack_weights_kernel(
    const float* __restrict__ w1, const float* __restrict__ b1,
    const float* __restrict__ w2, unsigned short* __restrict__ w1p,
    unsigned short* __restrict__ w2p) {
  const int tid = blockIdx.x * 256 + threadIdx.x;
  if (tid < 1024) {
    const int l = tid & 63, m = (tid >> 6) & 7, ks = (tid >> 9) & 1;
    const int row = m * 16 + (l & 15);
    const int kb = ks * 32 + (l >> 4) * 8;
    const size_t off = (((size_t)ks * 8 + m) * 64 + l) * 8;
#pragma unroll
    for (int j = 0; j < 8; ++j) {
      const int k = kb + j;          // k'' in [0,64)
      const int cc = k >> 2, f = k & 3;
      const float v = (f < 3) ? w1[row * 48 + cc * 3 + f]
                              : ((k == 3) ? b1[row] : 0.0f);
      w1p[off + j] = f2bf(v);
    }
  } else if (tid < 1280) {
    const int t2 = tid - 1024;
    const int l = t2 & 63, ks = (t2 >> 6) & 3;
    const int row = l & 15;
    const int kb = ks * 32 + (l >> 4) * 8;
    const size_t off = ((size_t)ks * 64 + l) * 8;
#pragma unroll
    for (int j = 0; j < 8; ++j) w2p[off + j] = f2bf(w2[row * 128 + kb + j]);
  }
}

// Swizzle key (bytes): mixes writer-varying bits (row>>2) with reader-varying
// bits (row&3) so all Y/H access patterns are 2-way (free). row in [0,16).
__device__ inline int swkey(int row) {
  return (((row >> 2) ^ ((row & 3) << 2)) & 15) << 3;
}

// ---------------------------------------------------------------- main
// Block = 64 px (quarter row), 256 thr = 4 waves; wave wv owns the 16-px
// tile at gcol [wt*64 + wv*16, +16). Thread roles: filter (c=ln, quad=g);
// GEMM1/GEMM2 (px-row = ln, k-group = g). Per-wave LDS: Y 2 KB @ wv*2048,
// H 4 KB @ 8192 + wv*4096 (24 KB total). NO barriers.
__global__ __launch_bounds__(256, 4) void nca_mfma_kernel(
    const float* __restrict__ x, const float* __restrict__ b2,
    const unsigned short* __restrict__ w1p,
    const unsigned short* __restrict__ w2p, const int* __restrict__ fire,
    float* __restrict__ out, float* __restrict__ alpha_ws,
    unsigned char* __restrict__ pre_ws) {
  __shared__ __align__(16) unsigned char smem[24576];

  const int L = blockIdx.x;
  const int orig = ((L & 7) << 12) | (L >> 3);  // XCD swizzle (32768 = 8*4096)
  const int b = orig >> 10;
  const int h = (orig >> 2) & 255;
  const int wt = orig & 3;
  const int tid = threadIdx.x;
  const int wv = tid >> 6, lane = tid & 63, g = lane >> 4, ln = lane & 15;
  const int tilebase = wt * 64 + wv * 16;
  const int hm = (h + 255) & 255, hp = (h + 1) & 255;

  unsigned char* Ys = smem + wv * 2048;          // 16 rows x 128 B
  unsigned char* Hsm = smem + 8192 + wv * 4096;  // 16 rows x 256 B

  // ---- x loads first (deepest latency), then A1 preload (16 frags).
  const int c = ln;       // filter channel
  const int quad = g;     // px quad within tile
  const int gcol0 = tilebase + quad * 4;
  const float* xc = x + (size_t)(b * CCH + c) * (HH * WW);
  const f32x4 t4 = *(const f32x4*)(xc + (size_t)hm * WW + gcol0);
  const f32x4 m4 = *(const f32x4*)(xc + (size_t)h * WW + gcol0);
  const f32x4 o4 = *(const f32x4*)(xc + (size_t)hp * WW + gcol0);

  bf16x8 A1[8][2];  // [mt][ks] — 64 VGPRs, loads hide under the filter
#pragma unroll
  for (int mt = 0; mt < 8; ++mt)
#pragma unroll
    for (int ks = 0; ks < 2; ++ks)
      A1[mt][ks] =
          *(const bf16x8*)(w1p + (((size_t)ks * 8 + mt) * 64 + lane) * 8);

  // ---- filter: vertical then horizontal (shuffle lane+-16), Y -> LDS.
  f32x4 av, bv;
#pragma unroll
  for (int j = 0; j < 4; ++j) {
    av[j] = 0.125f * (t4[j] + o4[j]) + 0.25f * m4[j];
    bv[j] = 0.125f * (o4[j] - t4[j]);
  }
  float haA = 0.f, haB = 0.f, hcm = 0.f;
  if (quad == 0 || quad == 3) {  // tile-edge halo columns (global loads)
    const int gc = (quad == 3) ? ((tilebase + 16) & 255)
                               : ((tilebase + 255) & 255);
    const float t = xc[(size_t)hm * WW + gc];
    const float m = xc[(size_t)h * WW + gc];
    const float bo = xc[(size_t)hp * WW + gc];
    haA = 0.125f * (t + bo) + 0.25f * m;
    haB = 0.125f * (bo - t);
    hcm = fmaxf(fmaxf(t, m), bo);
  }
  {
    float aLs = __shfl(av[3], lane - 16, 64);
    float bLs = __shfl(bv[3], lane - 16, 64);
    float aRs = __shfl(av[0], lane + 16, 64);
    float bRs = __shfl(bv[0], lane + 16, 64);
    if (quad == 0) { aLs = haA; bLs = haB; }
    if (quad == 3) { aRs = haA; bRs = haB; }

    const int c8 = c * 8;
    const float padv = (c == 0) ? 1.0f : 0.0f;  // bias-column activation
#pragma unroll
    for (int i = 0; i < 4; ++i) {
      const float aR = (i < 3) ? av[i + 1] : aRs;
      const float aL = (i > 0) ? av[i - 1] : aLs;
      const float bR = (i < 3) ? bv[i + 1] : bRs;
      const float bL = (i > 0) ? bv[i - 1] : bLs;
      const int row = quad * 4 + i;  // px within tile
      u32x2 w;
      w[0] = cvtpk2(m4[i], aR - aL);
      w[1] = cvtpk2(bL + 2.0f * bv[i] + bR, padv);
      *(u32x2*)(Ys + row * 128 + (c8 ^ swkey(row))) = w;
    }

    if (c == 3) {  // pre-life: 3x3 colmax for this quad's 4 px
      f32x4 cm4;
#pragma unroll
      for (int j = 0; j < 4; ++j) cm4[j] = fmaxf(fmaxf(t4[j], m4[j]), o4[j]);
      float cmL = __shfl(cm4[3], lane - 16, 64);
      float cmR = __shfl(cm4[0], lane + 16, 64);
      if (quad == 0) cmL = hcm;
      if (quad == 3) cmR = hcm;
      const float p0 = fmaxf(fmaxf(cmL, cm4[0]), cm4[1]);
      const float p1 = fmaxf(fmaxf(cm4[0], cm4[1]), cm4[2]);
      const float p2 = fmaxf(fmaxf(cm4[1], cm4[2]), cm4[3]);
      const float p3 = fmaxf(fmaxf(cm4[2], cm4[3]), cmR);
      const unsigned int pb = (p0 > 0.1f ? 1u : 0u) |
                              ((p1 > 0.1f ? 1u : 0u) << 8) |
                              ((p2 > 0.1f ? 1u : 0u) << 16) |
                              ((p3 > 0.1f ? 1u : 0u) << 24);
      *(unsigned int*)(pre_ws + ((size_t)b * HH + h) * WW + gcol0) = pb;
    }
  }
  // No barrier: Y for this tile is wave-local (lgkmcnt orders RAW).

  // ---- GEMM1: all 8 M-tiles, N = 16 px (this wave's tile).
  const int sk = swkey(ln);
  {
    const unsigned char* rb = Ys + ln * 128;
    bfpack B0, B1;
    B0.w2[0] = *(const u32x2*)(rb + ((g * 16) ^ sk));
    B0.w2[1] = *(const u32x2*)(rb + ((g * 16 + 8) ^ sk));
    B1.w2[0] = *(const u32x2*)(rb + ((64 + g * 16) ^ sk));
    B1.w2[1] = *(const u32x2*)(rb + ((64 + g * 16 + 8) ^ sk));

    // A2 loads issued here: in flight across the 16-MFMA mt loop.
    bf16x8 A2[4];
#pragma unroll
    for (int i = 0; i < 4; ++i)
      A2[i] = *(const bf16x8*)(w2p + ((size_t)i * 64 + lane) * 8);

#pragma unroll
    for (int mt = 0; mt < 8; ++mt) {
      f32x4 a = (f32x4){0.f, 0.f, 0.f, 0.f};
      a = __builtin_amdgcn_mfma_f32_16x16x32_bf16(A1[mt][0], B0.v, a, 0, 0, 0);
      a = __builtin_amdgcn_mfma_f32_16x16x32_bf16(A1[mt][1], B1.v, a, 0, 0, 0);
      const int hid0 = mt * 16 + g * 4;
      u32x2 hv;
      hv[0] = cvtpk2(fmaxf(a[0], 0.f), fmaxf(a[1], 0.f));
      hv[1] = cvtpk2(fmaxf(a[2], 0.f), fmaxf(a[3], 0.f));
      *(u32x2*)(Hsm + ln * 256 + ((hid0 * 2) ^ sk)) = hv;
    }

    // ---- GEMM2: dx = W2 . H (transposed: A = H frag, B = W2), N = 16 ch.
    const unsigned char* rb2 = Hsm + ln * 256;
    f32x4 a = (f32x4){0.f, 0.f, 0.f, 0.f};
#pragma unroll
    for (int ks = 0; ks < 4; ++ks) {
      const int o = ks * 64 + g * 16;
      bfpack Hf;
      Hf.w2[0] = *(const u32x2*)(rb2 + (o ^ sk));
      Hf.w2[1] = *(const u32x2*)(rb2 + ((o + 8) ^ sk));
      a = __builtin_amdgcn_mfma_f32_16x16x32_bf16(Hf.v, A2[ks], a, 0, 0, 0);
    }

    // ---- epilogue: C-frag ch = ln, px = tilebase + g*4 + r.
    const int px0 = tilebase + g * 4;
    const size_t pix0 = ((size_t)b * HH + h) * WW + px0;
    const i32x4 fi = *(const i32x4*)(fire + pix0);
    const float b2v = b2[ln];
    const size_t xi0 = (((size_t)(b * CCH + ln)) * HH + h) * WW + px0;
    const f32x4 xo = *(const f32x4*)(x + xi0);
    f32x4 v;
#pragma unroll
    for (int r = 0; r < 4; ++r) v[r] = xo[r] + (a[r] + b2v) * (float)fi[r];
    *(f32x4*)(out + xi0) = v;
    if (ln == 3) *(f32x4*)(alpha_ws + pix0) = v;
  }
}

// ---------------------------------------------------------------- life
// 4 px/thread; one wave = one full 256-px row; wrap shuffles, no halo loads.
__global__ __launch_bounds__(256) void life_mask_kernel(
    const float* __restrict__ alpha_ws, const unsigned char* __restrict__ pre_ws,
    float* __restrict__ out) {
  const int idx = blockIdx.x * 256 + threadIdx.x;  // npix/4 threads
  const int lane = idx & 63;
  const int w0 = lane * 4;
  const int h = (idx >> 6) & 255;
  const int b = idx >> 14;
  const int hm = (h + 255) & 255;
  const int hp = (h + 1) & 255;

  const float* ab = alpha_ws + (size_t)b * HH * WW;
  const f32x4 up = *(const f32x4*)(ab + (size_t)hm * WW + w0);
  const f32x4 mi = *(const f32x4*)(ab + (size_t)h * WW + w0);
  const f32x4 dn = *(const f32x4*)(ab + (size_t)hp * WW + w0);
  f32x4 cm;
#pragma unroll
  for (int j = 0; j < 4; ++j) cm[j] = fmaxf(fmaxf(up[j], mi[j]), dn[j]);

  const float cmL = __shfl(cm[3], (lane + 63) & 63, 64);  // wrap
  const float cmR = __shfl(cm[0], (lane + 1) & 63, 64);   // wrap
  const float p0 = fmaxf(fmaxf(cmL, cm[0]), cm[1]);
  const float p1 = fmaxf(fmaxf(cm[0], cm[1]), cm[2]);
  const float p2 = fmaxf(fmaxf(cm[1], cm[2]), cm[3]);
  const float p3 = fmaxf(fmaxf(cm[2], cm[3]), cmR);

  const size_t pix0 = ((size_t)b * HH + h) * WW + w0;
  const unsigned int pb = *(const unsigned int*)(pre_ws + pix0);
  const bool l0 = (p0 > 0.1f) && (pb & 0xFFu);
  const bool l1 = (p1 > 0.1f) && (pb & 0xFF00u);
  const bool l2 = (p2 > 0.1f) && (pb & 0xFF0000u);
  const bool l3 = (p3 > 0.1f) && (pb & 0xFF000000u);

  if (!(l0 && l1 && l2 && l3)) {
    const bool lv[4] = {l0, l1, l2, l3};
#pragma unroll
    for (int r = 0; r < 4; ++r) {
      if (!lv[r]) {
        float* op = out + ((size_t)b * CCH * HH + h) * WW + w0 + r;
#pragma unroll
        for (int c = 0; c < CCH; ++c) op[(size_t)c * HH * WW] = 0.0f;
      }
    }
  }
}

// ---------------------------------------------------------------- launch
extern "C" void kernel_launch(void* const* d_in, const int* in_sizes, int n_in,
                              void* d_out, int out_size, void* d_ws,
                              size_t ws_size, hipStream_t stream) {
  const float* x = (const float*)d_in[0];
  const float* w1 = (const float*)d_in[1];
  const float* b1 = (const float*)d_in[2];
  const float* w2 = (const float*)d_in[3];
  const float* b2 = (const float*)d_in[4];
  const int* fire = (const int*)d_in[5];
  float* out = (float*)d_out;

  const size_t npix = (size_t)BB * HH * WW;
  unsigned short* w1p = (unsigned short*)d_ws;                   // 16 KB
  unsigned short* w2p = (unsigned short*)((char*)d_ws + 16384);  // 4 KB
  float* alpha_ws = (float*)((char*)d_ws + 40960);
  unsigned char* pre_ws = (unsigned char*)d_ws + 40960 + npix * sizeof(float);

  pack_weights_kernel<<<5, 256, 0, stream>>>(w1, b1, w2, w1p, w2p);
  nca_mfma_kernel<<<BB * HH * 4, 256, 0, stream>>>(x, b2, w1p, w2p, fire, out,
                                                   alpha_ws, pre_ws);
  life_mask_kernel<<<(int)(npix / 4 / 256), 256, 0, stream>>>(alpha_ws, pre_ws,
                                                              out);
}

// Round 21
// 140.293 us; speedup vs baseline: 1.6670x; 1.6670x over previous
//
#include <hip/hip_runtime.h>
#include <hip/hip_bf16.h>

// NCA update, round 21: R19 (141us) with FILTER(T2)'s arithmetic moved after
// barA so its VALU overlaps GEMM1(T1)'s MFMA (separate pipes, independent
// data). T2's x-loads stay hoisted before barA. Bit-identical to R19.

#define CCH 16
#define HID 128
#define HH 256
#define WW 256
#define BB 32

typedef __attribute__((ext_vector_type(8))) short bf16x8;
typedef __attribute__((ext_vector_type(4))) float f32x4;
typedef __attribute__((ext_vector_type(4))) int i32x4;
typedef __attribute__((ext_vector_type(2))) unsigned int u32x2;

union bfpack {
  u32x2 w2[2];
  bf16x8 v;
};

__device__ inline unsigned short f2bf(float f) {  // RNE
  unsigned int u = __float_as_uint(f);
  u += 0x7FFFu + ((u >> 16) & 1u);
  return (unsigned short)(u >> 16);
}
__device__ inline unsigned int cvtpk2(float a, float b) {  // v_cvt_pk_bf16_f32
  union { __hip_bfloat162 h; unsigned int u; } cv;
  cv.h = __float22bfloat162_rn(make_float2(a, b));
  return cv.u;
}

// ---------------------------------------------------------------- prep
// w1p[((ks*8 + mt)*64 + lane)*8 + j]; row = mt*16+(l&15),
// k'' = ks*32+(l>>4)*8+j; k''=c*4+f -> w1[row][c*3+f]; k''==3 -> b1[row]
// (bias column, pairs with Y[3]=1.0 at c==0); other f==3 -> 0. bf16 (hi only).
// w2p[(ks*64 + lane)*8 + j]; out-ch = l&15, k = ks*32+(l>>4)*8+j. bf16.
__global__ __launch_bounds__(256) void pack_weights_kernel(
    const float* __restrict__ w1, const float* __restrict__ b1,
    const float* __restrict__ w2, unsigned short* __restrict__ w1p,
    unsigned short* __restrict__ w2p) {
  const int tid = blockIdx.x * 256 + threadIdx.x;
  if (tid < 1024) {
    const int l = tid & 63, m = (tid >> 6) & 7, ks = (tid >> 9) & 1;
    const int row = m * 16 + (l & 15);
    const int kb = ks * 32 + (l >> 4) * 8;
    const size_t off = (((size_t)ks * 8 + m) * 64 + l) * 8;
#pragma unroll
    for (int j = 0; j < 8; ++j) {
      const int k = kb + j;          // k'' in [0,64)
      const int cc = k >> 2, f = k & 3;
      const float v = (f < 3) ? w1[row * 48 + cc * 3 + f]
                              : ((k == 3) ? b1[row] : 0.0f);
      w1p[off + j] = f2bf(v);
    }
  } else if (tid < 1280) {
    const int t2 = tid - 1024;
    const int l = t2 & 63, ks = (t2 >> 6) & 3;
    const int row = l & 15;
    const int kb = ks * 32 + (l >> 4) * 8;
    const size_t off = ((size_t)ks * 64 + l) * 8;
#pragma unroll
    for (int j = 0; j < 8; ++j) w2p[off + j] = f2bf(w2[row * 128 + kb + j]);
  }
}

// Swizzle key (bytes): mixes writer-varying bits (row>>2) with reader-varying
// bits (row&3) so all Y/H access patterns are 2-way (free).
__device__ inline int swkey(int row) {
  return (((row >> 2) ^ ((row & 3) << 2)) & 15) << 3;
}

// ---------------------------------------------------------------- main
// Block = two 64-px tiles of the same row h (wt = 2u, 2u+1), 256 thr = 4
// waves. T2's x rows load before barA; T2's filter ARITHMETIC runs after
// barA, overlapping GEMM1(T1)'s MFMA. T2's Y parked in 8 VGPRs, stored
// after barB. LDS 24576 B: Y row px*128, H row px*256, XOR swkey.
__global__ __launch_bounds__(256, 4) void nca_mfma_kernel(
    const float* __restrict__ x, const float* __restrict__ b2,
    const unsigned short* __restrict__ w1p,
    const unsigned short* __restrict__ w2p, const int* __restrict__ fire,
    float* __restrict__ out, float* __restrict__ alpha_ws,
    unsigned char* __restrict__ pre_ws) {
  __shared__ __align__(16) unsigned char smem[24576];
  unsigned char* Ys = smem;
  unsigned char* Hsm = smem + 8192;

  const int L = blockIdx.x;
  const int orig = ((L & 7) << 11) | (L >> 3);  // XCD swizzle (16384 = 8*2048)
  const int b = orig >> 9;
  const int h = (orig >> 1) & 255;
  const int u = orig & 1;
  const int wt1 = u * 2, wt2 = u * 2 + 1;
  const int tid = threadIdx.x;
  const int wv = tid >> 6, lane = tid & 63, g = lane >> 4, ln = lane & 15;
  const int c = wv * 4 + g;
  const int q = ln;
  const int hm = (h + 255) & 255, hp = (h + 1) & 255;
  const float* xc = x + (size_t)(b * CCH + c) * (HH * WW);
  const float padv = (c == 0) ? 1.0f : 0.0f;  // bias-column activation
  const bool edge = (q == 0 || q == 15);

  // ---- tile T1: full filter -> Y to LDS, pre-life (as R19).
  {
    const int gcol0 = wt1 * 64 + q * 4;
    const f32x4 t4 = *(const f32x4*)(xc + (size_t)hm * WW + gcol0);
    const f32x4 m4 = *(const f32x4*)(xc + (size_t)h * WW + gcol0);
    const f32x4 o4 = *(const f32x4*)(xc + (size_t)hp * WW + gcol0);
    f32x4 av, bv;
#pragma unroll
    for (int j = 0; j < 4; ++j) {
      av[j] = 0.125f * (t4[j] + o4[j]) + 0.25f * m4[j];
      bv[j] = 0.125f * (o4[j] - t4[j]);
    }
    float haA = 0.f, haB = 0.f, hcm = 0.f;
    if (edge) {
      const int gc =
          (q == 15) ? ((wt1 * 64 + 64) & 255) : ((wt1 * 64 + 255) & 255);
      const float t = xc[(size_t)hm * WW + gc];
      const float m = xc[(size_t)h * WW + gc];
      const float bo = xc[(size_t)hp * WW + gc];
      haA = 0.125f * (t + bo) + 0.25f * m;
      haB = 0.125f * (bo - t);
      hcm = fmaxf(fmaxf(t, m), bo);
    }
    float aLs = __shfl(av[3], lane - 1, 64);
    float bLs = __shfl(bv[3], lane - 1, 64);
    float aRs = __shfl(av[0], lane + 1, 64);
    float bRs = __shfl(bv[0], lane + 1, 64);
    if (q == 0) { aLs = haA; bLs = haB; }
    if (q == 15) { aRs = haA; bRs = haB; }

    const int c8 = c * 8;
#pragma unroll
    for (int i = 0; i < 4; ++i) {
      const float aR = (i < 3) ? av[i + 1] : aRs;
      const float aL = (i > 0) ? av[i - 1] : aLs;
      const float bR = (i < 3) ? bv[i + 1] : bRs;
      const float bL = (i > 0) ? bv[i - 1] : bLs;
      const int px = q * 4 + i;
      u32x2 w;
      w[0] = cvtpk2(m4[i], aR - aL);
      w[1] = cvtpk2(bL + 2.0f * bv[i] + bR, padv);
      *(u32x2*)(Ys + px * 128 + (c8 ^ swkey(px))) = w;
    }
    if (c == 3) {
      f32x4 cm4;
#pragma unroll
      for (int j = 0; j < 4; ++j) cm4[j] = fmaxf(fmaxf(t4[j], m4[j]), o4[j]);
      float cmL = __shfl(cm4[3], lane - 1, 64);
      float cmR = __shfl(cm4[0], lane + 1, 64);
      if (q == 0) cmL = hcm;
      if (q == 15) cmR = hcm;
      const float p0 = fmaxf(fmaxf(cmL, cm4[0]), cm4[1]);
      const float p1 = fmaxf(fmaxf(cm4[0], cm4[1]), cm4[2]);
      const float p2 = fmaxf(fmaxf(cm4[1], cm4[2]), cm4[3]);
      const float p3 = fmaxf(fmaxf(cm4[2], cm4[3]), cmR);
      const unsigned int pb = (p0 > 0.1f ? 1u : 0u) |
                              ((p1 > 0.1f ? 1u : 0u) << 8) |
                              ((p2 > 0.1f ? 1u : 0u) << 16) |
                              ((p3 > 0.1f ? 1u : 0u) << 24);
      *(unsigned int*)(pre_ws + ((size_t)b * HH + h) * WW + gcol0) = pb;
    }
  }

  // ---- tile T2: hoist x loads only (latency drains over barA).
  const int gcol0B = wt2 * 64 + q * 4;
  const f32x4 t4B = *(const f32x4*)(xc + (size_t)hm * WW + gcol0B);
  const f32x4 m4B = *(const f32x4*)(xc + (size_t)h * WW + gcol0B);
  const f32x4 o4B = *(const f32x4*)(xc + (size_t)hp * WW + gcol0B);
  float htB = 0.f, hmB = 0.f, hoB = 0.f;  // raw halo values (edge lanes)
  if (edge) {
    const int gc =
        (q == 15) ? ((wt2 * 64 + 64) & 255) : ((wt2 * 64 + 255) & 255);
    htB = xc[(size_t)hm * WW + gc];
    hmB = xc[(size_t)h * WW + gc];
    hoB = xc[(size_t)hp * WW + gc];
  }

  // A1 (bf16 W1): loaded once, serves both tiles (issued before barA).
  bf16x8 A1[2][2];  // [mi][ks] for mt = 2wv+mi
#pragma unroll
  for (int mi = 0; mi < 2; ++mi)
#pragma unroll
    for (int ks = 0; ks < 2; ++ks)
      A1[mi][ks] = *(const bf16x8*)(
          w1p + (((size_t)ks * 8 + (wv * 2 + mi)) * 64 + lane) * 8);

  // GEMM1: Y(LDS) -> relu -> H(LDS); bias accumulates inside the MFMA.
  auto GEMM1 = [&]() {
#pragma unroll
    for (int ni = 0; ni < 4; ++ni) {
      const int pxb = ni * 16 + ln;
      const int sk = swkey(pxb);
      const unsigned char* rb = Ys + pxb * 128;
      bfpack B0, B1;
      B0.w2[0] = *(const u32x2*)(rb + ((g * 16) ^ sk));
      B0.w2[1] = *(const u32x2*)(rb + ((g * 16 + 8) ^ sk));
      B1.w2[0] = *(const u32x2*)(rb + ((64 + g * 16) ^ sk));
      B1.w2[1] = *(const u32x2*)(rb + ((64 + g * 16 + 8) ^ sk));
#pragma unroll
      for (int mi = 0; mi < 2; ++mi) {
        f32x4 a = (f32x4){0.f, 0.f, 0.f, 0.f};
        a = __builtin_amdgcn_mfma_f32_16x16x32_bf16(A1[mi][0], B0.v, a, 0, 0, 0);
        a = __builtin_amdgcn_mfma_f32_16x16x32_bf16(A1[mi][1], B1.v, a, 0, 0, 0);
        const int hid0 = (wv * 2 + mi) * 16 + g * 4;
        u32x2 hv;
        hv[0] = cvtpk2(fmaxf(a[0], 0.f), fmaxf(a[1], 0.f));
        hv[1] = cvtpk2(fmaxf(a[2], 0.f), fmaxf(a[3], 0.f));
        *(u32x2*)(Hsm + pxb * 256 + ((hid0 * 2) ^ sk)) = hv;
      }
    }
  };

  // GEMM2(wt_): H(LDS) -> out/alpha; W2 bf16 (hi only).
  auto GEMM2 = [&](int wt_) {
    bf16x8 A2[4];
#pragma unroll
    for (int i = 0; i < 4; ++i)
      A2[i] = *(const bf16x8*)(w2p + ((size_t)i * 64 + lane) * 8);

    const int px0 = wv * 16 + g * 4;
    const int wg0 = wt_ * 64 + px0;
    const size_t pix0 = ((size_t)b * HH + h) * WW + wg0;
    const i32x4 fi = *(const i32x4*)(fire + pix0);
    const float b2v = b2[ln];
    const size_t xi0 = (((size_t)(b * CCH + ln)) * HH + h) * WW + wg0;
    const f32x4 xo = *(const f32x4*)(x + xi0);

    const int prow = wv * 16 + ln;
    const int sk = swkey(prow);
    const unsigned char* rb = Hsm + prow * 256;
    f32x4 a = (f32x4){0.f, 0.f, 0.f, 0.f};
#pragma unroll
    for (int ks = 0; ks < 4; ++ks) {
      const int o = ks * 64 + g * 16;
      bfpack Hf;
      Hf.w2[0] = *(const u32x2*)(rb + (o ^ sk));
      Hf.w2[1] = *(const u32x2*)(rb + ((o + 8) ^ sk));
      a = __builtin_amdgcn_mfma_f32_16x16x32_bf16(Hf.v, A2[ks], a, 0, 0, 0);
    }
    f32x4 v;
#pragma unroll
    for (int r = 0; r < 4; ++r) v[r] = xo[r] + (a[r] + b2v) * (float)fi[r];
    *(f32x4*)(out + xi0) = v;
    if (ln == 3) *(f32x4*)(alpha_ws + pix0) = v;
  };

  __syncthreads();  // barA: Y-T1 visible

  // ---- region A: GEMM1(T1) MFMA + FILTER-compute(T2) VALU co-scheduled.
  u32x2 yP[4];  // T2's packed Y
  GEMM1();      // T1: Y -> H
  {
    f32x4 av, bv;
#pragma unroll
    for (int j = 0; j < 4; ++j) {
      av[j] = 0.125f * (t4B[j] + o4B[j]) + 0.25f * m4B[j];
      bv[j] = 0.125f * (o4B[j] - t4B[j]);
    }
    float haA = 0.f, haB = 0.f, hcm = 0.f;
    if (edge) {
      haA = 0.125f * (htB + hoB) + 0.25f * hmB;
      haB = 0.125f * (hoB - htB);
      hcm = fmaxf(fmaxf(htB, hmB), hoB);
    }
    float aLs = __shfl(av[3], lane - 1, 64);
    float bLs = __shfl(bv[3], lane - 1, 64);
    float aRs = __shfl(av[0], lane + 1, 64);
    float bRs = __shfl(bv[0], lane + 1, 64);
    if (q == 0) { aLs = haA; bLs = haB; }
    if (q == 15) { aRs = haA; bRs = haB; }

#pragma unroll
    for (int i = 0; i < 4; ++i) {
      const float aR = (i < 3) ? av[i + 1] : aRs;
      const float aL = (i > 0) ? av[i - 1] : aLs;
      const float bR = (i < 3) ? bv[i + 1] : bRs;
      const float bL = (i > 0) ? bv[i - 1] : bLs;
      yP[i][0] = cvtpk2(m4B[i], aR - aL);
      yP[i][1] = cvtpk2(bL + 2.0f * bv[i] + bR, padv);
    }
    if (c == 3) {
      f32x4 cm4;
#pragma unroll
      for (int j = 0; j < 4; ++j)
        cm4[j] = fmaxf(fmaxf(t4B[j], m4B[j]), o4B[j]);
      float cmL = __shfl(cm4[3], lane - 1, 64);
      float cmR = __shfl(cm4[0], lane + 1, 64);
      if (q == 0) cmL = hcm;
      if (q == 15) cmR = hcm;
      const float p0 = fmaxf(fmaxf(cmL, cm4[0]), cm4[1]);
      const float p1 = fmaxf(fmaxf(cm4[0], cm4[1]), cm4[2]);
      const float p2 = fmaxf(fmaxf(cm4[1], cm4[2]), cm4[3]);
      const float p3 = fmaxf(fmaxf(cm4[2], cm4[3]), cmR);
      const unsigned int pb = (p0 > 0.1f ? 1u : 0u) |
                              ((p1 > 0.1f ? 1u : 0u) << 8) |
                              ((p2 > 0.1f ? 1u : 0u) << 16) |
                              ((p3 > 0.1f ? 1u : 0u) << 24);
      *(unsigned int*)(pre_ws + ((size_t)b * HH + h) * WW + gcol0B) = pb;
    }
  }

  __syncthreads();  // barB: H-T1 visible; all Y-T1 reads drained
  {                 // park T2's Y into the freed Y region
    const int c8 = c * 8;
#pragma unroll
    for (int i = 0; i < 4; ++i) {
      const int px = q * 4 + i;
      *(u32x2*)(Ys + px * 128 + (c8 ^ swkey(px))) = yP[i];
    }
  }
  GEMM2(wt1);       // T1 epilogue (overlaps the park stores)
  __syncthreads();  // barC: Y-T2 visible; all H-T1 reads drained
  GEMM1();          // T2
  __syncthreads();  // barD: H-T2 visible
  GEMM2(wt2);       // T2 epilogue
}

// ---------------------------------------------------------------- life
// 4 px/thread; one wave = one full 256-px row; wrap shuffles, no halo loads.
__global__ __launch_bounds__(256) void life_mask_kernel(
    const float* __restrict__ alpha_ws, const unsigned char* __restrict__ pre_ws,
    float* __restrict__ out) {
  const int idx = blockIdx.x * 256 + threadIdx.x;  // npix/4 threads
  const int lane = idx & 63;
  const int w0 = lane * 4;
  const int h = (idx >> 6) & 255;
  const int b = idx >> 14;
  const int hm = (h + 255) & 255;
  const int hp = (h + 1) & 255;

  const float* ab = alpha_ws + (size_t)b * HH * WW;
  const f32x4 up = *(const f32x4*)(ab + (size_t)hm * WW + w0);
  const f32x4 mi = *(const f32x4*)(ab + (size_t)h * WW + w0);
  const f32x4 dn = *(const f32x4*)(ab + (size_t)hp * WW + w0);
  f32x4 cm;
#pragma unroll
  for (int j = 0; j < 4; ++j) cm[j] = fmaxf(fmaxf(up[j], mi[j]), dn[j]);

  const float cmL = __shfl(cm[3], (lane + 63) & 63, 64);  // wrap
  const float cmR = __shfl(cm[0], (lane + 1) & 63, 64);   // wrap
  const float p0 = fmaxf(fmaxf(cmL, cm[0]), cm[1]);
  const float p1 = fmaxf(fmaxf(cm[0], cm[1]), cm[2]);
  const float p2 = fmaxf(fmaxf(cm[1], cm[2]), cm[3]);
  const float p3 = fmaxf(fmaxf(cm[2], cm[3]), cmR);

  const size_t pix0 = ((size_t)b * HH + h) * WW + w0;
  const unsigned int pb = *(const unsigned int*)(pre_ws + pix0);
  const bool l0 = (p0 > 0.1f) && (pb & 0xFFu);
  const bool l1 = (p1 > 0.1f) && (pb & 0xFF00u);
  const bool l2 = (p2 > 0.1f) && (pb & 0xFF0000u);
  const bool l3 = (p3 > 0.1f) && (pb & 0xFF000000u);

  if (!(l0 && l1 && l2 && l3)) {
    const bool lv[4] = {l0, l1, l2, l3};
#pragma unroll
    for (int r = 0; r < 4; ++r) {
      if (!lv[r]) {
        float* op = out + ((size_t)b * CCH * HH + h) * WW + w0 + r;
#pragma unroll
        for (int c = 0; c < CCH; ++c) op[(size_t)c * HH * WW] = 0.0f;
      }
    }
  }
}

// ---------------------------------------------------------------- launch
extern "C" void kernel_launch(void* const* d_in, const int* in_sizes, int n_in,
                              void* d_out, int out_size, void* d_ws,
                              size_t ws_size, hipStream_t stream) {
  const float* x = (const float*)d_in[0];
  const float* w1 = (const float*)d_in[1];
  const float* b1 = (const float*)d_in[2];
  const float* w2 = (const float*)d_in[3];
  const float* b2 = (const float*)d_in[4];
  const int* fire = (const int*)d_in[5];
  float* out = (float*)d_out;

  const size_t npix = (size_t)BB * HH * WW;
  unsigned short* w1p = (unsigned short*)d_ws;                   // 16 KB
  unsigned short* w2p = (unsigned short*)((char*)d_ws + 16384);  // 4 KB
  float* alpha_ws = (float*)((char*)d_ws + 40960);
  unsigned char* pre_ws = (unsigned char*)d_ws + 40960 + npix * sizeof(float);

  pack_weights_kernel<<<5, 256, 0, stream>>>(w1, b1, w2, w1p, w2p);
  nca_mfma_kernel<<<BB * HH * 2, 256, 0, stream>>>(x, b2, w1p, w2p, fire, out,
                                                   alpha_ws, pre_ws);
  life_mask_kernel<<<(int)(npix / 4 / 256), 256, 0, stream>>>(alpha_ws, pre_ws,
                                                              out);
}

// Round 22
// 139.517 us; speedup vs baseline: 1.6763x; 1.0056x over previous
//
#include <hip/hip_runtime.h>
#include <hip/hip_bf16.h>

// NCA update, round 22: R21 + (1) epilogue fire/x loads for both tiles
// hoisted before barA (fire is the cold stream; ~900cy now hidden under
// filter+GEMM1), (2) filter arithmetic as f32x4 vector expressions to
// enable packed v_pk_* fp32 math. Bit-identical numerics to R21.

#define CCH 16
#define HID 128
#define HH 256
#define WW 256
#define BB 32

typedef __attribute__((ext_vector_type(8))) short bf16x8;
typedef __attribute__((ext_vector_type(4))) float f32x4;
typedef __attribute__((ext_vector_type(4))) int i32x4;
typedef __attribute__((ext_vector_type(2))) unsigned int u32x2;

union bfpack {
  u32x2 w2[2];
  bf16x8 v;
};

__device__ inline unsigned short f2bf(float f) {  // RNE
  unsigned int u = __float_as_uint(f);
  u += 0x7FFFu + ((u >> 16) & 1u);
  return (unsigned short)(u >> 16);
}
__device__ inline unsigned int cvtpk2(float a, float b) {  // v_cvt_pk_bf16_f32
  union { __hip_bfloat162 h; unsigned int u; } cv;
  cv.h = __float22bfloat162_rn(make_float2(a, b));
  return cv.u;
}

// ---------------------------------------------------------------- prep
// w1p[((ks*8 + mt)*64 + lane)*8 + j]; row = mt*16+(l&15),
// k'' = ks*32+(l>>4)*8+j; k''=c*4+f -> w1[row][c*3+f]; k''==3 -> b1[row]
// (bias column, pairs with Y[3]=1.0 at c==0); other f==3 -> 0. bf16 (hi only).
// w2p[(ks*64 + lane)*8 + j]; out-ch = l&15, k = ks*32+(l>>4)*8+j. bf16.
__global__ __launch_bounds__(256) void pack_weights_kernel(
    const float* __restrict__ w1, const float* __restrict__ b1,
    const float* __restrict__ w2, unsigned short* __restrict__ w1p,
    unsigned short* __restrict__ w2p) {
  const int tid = blockIdx.x * 256 + threadIdx.x;
  if (tid < 1024) {
    const int l = tid & 63, m = (tid >> 6) & 7, ks = (tid >> 9) & 1;
    const int row = m * 16 + (l & 15);
    const int kb = ks * 32 + (l >> 4) * 8;
    const size_t off = (((size_t)ks * 8 + m) * 64 + l) * 8;
#pragma unroll
    for (int j = 0; j < 8; ++j) {
      const int k = kb + j;          // k'' in [0,64)
      const int cc = k >> 2, f = k & 3;
      const float v = (f < 3) ? w1[row * 48 + cc * 3 + f]
                              : ((k == 3) ? b1[row] : 0.0f);
      w1p[off + j] = f2bf(v);
    }
  } else if (tid < 1280) {
    const int t2 = tid - 1024;
    const int l = t2 & 63, ks = (t2 >> 6) & 3;
    const int row = l & 15;
    const int kb = ks * 32 + (l >> 4) * 8;
    const size_t off = ((size_t)ks * 64 + l) * 8;
#pragma unroll
    for (int j = 0; j < 8; ++j) w2p[off + j] = f2bf(w2[row * 128 + kb + j]);
  }
}

// Swizzle key (bytes): mixes writer-varying bits (row>>2) with reader-varying
// bits (row&3) so all Y/H access patterns are 2-way (free).
__device__ inline int swkey(int row) {
  return (((row >> 2) ^ ((row & 3) << 2)) & 15) << 3;
}

// ---------------------------------------------------------------- main
// Block = two 64-px tiles of the same row h (wt = 2u, 2u+1), 256 thr = 4
// waves. All global loads for T2 + both epilogues hoisted before barA;
// T2's filter arithmetic overlaps GEMM1(T1). T2's Y parked in 8 VGPRs.
// LDS 24576 B: Y row px*128, H row px*256, XOR swkey.
__global__ __launch_bounds__(256, 4) void nca_mfma_kernel(
    const float* __restrict__ x, const float* __restrict__ b2,
    const unsigned short* __restrict__ w1p,
    const unsigned short* __restrict__ w2p, const int* __restrict__ fire,
    float* __restrict__ out, float* __restrict__ alpha_ws,
    unsigned char* __restrict__ pre_ws) {
  __shared__ __align__(16) unsigned char smem[24576];
  unsigned char* Ys = smem;
  unsigned char* Hsm = smem + 8192;

  const int L = blockIdx.x;
  const int orig = ((L & 7) << 11) | (L >> 3);  // XCD swizzle (16384 = 8*2048)
  const int b = orig >> 9;
  const int h = (orig >> 1) & 255;
  const int u = orig & 1;
  const int wt1 = u * 2, wt2 = u * 2 + 1;
  const int tid = threadIdx.x;
  const int wv = tid >> 6, lane = tid & 63, g = lane >> 4, ln = lane & 15;
  const int c = wv * 4 + g;
  const int q = ln;
  const int hm = (h + 255) & 255, hp = (h + 1) & 255;
  const float* xc = x + (size_t)(b * CCH + c) * (HH * WW);
  const float padv = (c == 0) ? 1.0f : 0.0f;  // bias-column activation
  const bool edge = (q == 0 || q == 15);

  // ---- tile T1: full filter -> Y to LDS, pre-life (vector-expr math).
  {
    const int gcol0 = wt1 * 64 + q * 4;
    const f32x4 t4 = *(const f32x4*)(xc + (size_t)hm * WW + gcol0);
    const f32x4 m4 = *(const f32x4*)(xc + (size_t)h * WW + gcol0);
    const f32x4 o4 = *(const f32x4*)(xc + (size_t)hp * WW + gcol0);
    const f32x4 av = 0.125f * (t4 + o4) + 0.25f * m4;
    const f32x4 bv = 0.125f * (o4 - t4);
    float haA = 0.f, haB = 0.f, hcm = 0.f;
    if (edge) {
      const int gc =
          (q == 15) ? ((wt1 * 64 + 64) & 255) : ((wt1 * 64 + 255) & 255);
      const float t = xc[(size_t)hm * WW + gc];
      const float m = xc[(size_t)h * WW + gc];
      const float bo = xc[(size_t)hp * WW + gc];
      haA = 0.125f * (t + bo) + 0.25f * m;
      haB = 0.125f * (bo - t);
      hcm = fmaxf(fmaxf(t, m), bo);
    }
    float aLs = __shfl(av[3], lane - 1, 64);
    float bLs = __shfl(bv[3], lane - 1, 64);
    float aRs = __shfl(av[0], lane + 1, 64);
    float bRs = __shfl(bv[0], lane + 1, 64);
    if (q == 0) { aLs = haA; bLs = haB; }
    if (q == 15) { aRs = haA; bRs = haB; }

    const int c8 = c * 8;
#pragma unroll
    for (int i = 0; i < 4; ++i) {
      const float aR = (i < 3) ? av[i + 1] : aRs;
      const float aL = (i > 0) ? av[i - 1] : aLs;
      const float bR = (i < 3) ? bv[i + 1] : bRs;
      const float bL = (i > 0) ? bv[i - 1] : bLs;
      const int px = q * 4 + i;
      u32x2 w;
      w[0] = cvtpk2(m4[i], aR - aL);
      w[1] = cvtpk2(bL + 2.0f * bv[i] + bR, padv);
      *(u32x2*)(Ys + px * 128 + (c8 ^ swkey(px))) = w;
    }
    if (c == 3) {
      f32x4 cm4;
#pragma unroll
      for (int j = 0; j < 4; ++j) cm4[j] = fmaxf(fmaxf(t4[j], m4[j]), o4[j]);
      float cmL = __shfl(cm4[3], lane - 1, 64);
      float cmR = __shfl(cm4[0], lane + 1, 64);
      if (q == 0) cmL = hcm;
      if (q == 15) cmR = hcm;
      const float p0 = fmaxf(fmaxf(cmL, cm4[0]), cm4[1]);
      const float p1 = fmaxf(fmaxf(cm4[0], cm4[1]), cm4[2]);
      const float p2 = fmaxf(fmaxf(cm4[1], cm4[2]), cm4[3]);
      const float p3 = fmaxf(fmaxf(cm4[2], cm4[3]), cmR);
      const unsigned int pb = (p0 > 0.1f ? 1u : 0u) |
                              ((p1 > 0.1f ? 1u : 0u) << 8) |
                              ((p2 > 0.1f ? 1u : 0u) << 16) |
                              ((p3 > 0.1f ? 1u : 0u) << 24);
      *(unsigned int*)(pre_ws + ((size_t)b * HH + h) * WW + gcol0) = pb;
    }
  }

  // ---- tile T2: hoist x loads only (latency drains over barA).
  const int gcol0B = wt2 * 64 + q * 4;
  const f32x4 t4B = *(const f32x4*)(xc + (size_t)hm * WW + gcol0B);
  const f32x4 m4B = *(const f32x4*)(xc + (size_t)h * WW + gcol0B);
  const f32x4 o4B = *(const f32x4*)(xc + (size_t)hp * WW + gcol0B);
  float htB = 0.f, hmB = 0.f, hoB = 0.f;  // raw halo values (edge lanes)
  if (edge) {
    const int gc =
        (q == 15) ? ((wt2 * 64 + 64) & 255) : ((wt2 * 64 + 255) & 255);
    htB = xc[(size_t)hm * WW + gc];
    hmB = xc[(size_t)h * WW + gc];
    hoB = xc[(size_t)hp * WW + gc];
  }

  // ---- epilogue loads for BOTH tiles hoisted here (fire is the cold
  // stream: ~900cy HBM latency now hidden under filter-T2 + GEMM1).
  const int epx1 = wt1 * 64 + wv * 16 + g * 4;   // tile-1 epilogue px0
  const int epx2 = wt2 * 64 + wv * 16 + g * 4;   // tile-2 epilogue px0
  const size_t pixE1 = ((size_t)b * HH + h) * WW + epx1;
  const size_t pixE2 = ((size_t)b * HH + h) * WW + epx2;
  const size_t xiE1 = (((size_t)(b * CCH + ln)) * HH + h) * WW + epx1;
  const size_t xiE2 = (((size_t)(b * CCH + ln)) * HH + h) * WW + epx2;
  const i32x4 fi1 = *(const i32x4*)(fire + pixE1);
  const i32x4 fi2 = *(const i32x4*)(fire + pixE2);
  const f32x4 xo1 = *(const f32x4*)(x + xiE1);
  const f32x4 xo2 = *(const f32x4*)(x + xiE2);
  const float b2v = b2[ln];

  // A1 (bf16 W1): loaded once, serves both tiles (issued before barA).
  bf16x8 A1[2][2];  // [mi][ks] for mt = 2wv+mi
#pragma unroll
  for (int mi = 0; mi < 2; ++mi)
#pragma unroll
    for (int ks = 0; ks < 2; ++ks)
      A1[mi][ks] = *(const bf16x8*)(
          w1p + (((size_t)ks * 8 + (wv * 2 + mi)) * 64 + lane) * 8);

  // GEMM1: Y(LDS) -> relu -> H(LDS); bias accumulates inside the MFMA.
  auto GEMM1 = [&]() {
#pragma unroll
    for (int ni = 0; ni < 4; ++ni) {
      const int pxb = ni * 16 + ln;
      const int sk = swkey(pxb);
      const unsigned char* rb = Ys + pxb * 128;
      bfpack B0, B1;
      B0.w2[0] = *(const u32x2*)(rb + ((g * 16) ^ sk));
      B0.w2[1] = *(const u32x2*)(rb + ((g * 16 + 8) ^ sk));
      B1.w2[0] = *(const u32x2*)(rb + ((64 + g * 16) ^ sk));
      B1.w2[1] = *(const u32x2*)(rb + ((64 + g * 16 + 8) ^ sk));
#pragma unroll
      for (int mi = 0; mi < 2; ++mi) {
        f32x4 a = (f32x4){0.f, 0.f, 0.f, 0.f};
        a = __builtin_amdgcn_mfma_f32_16x16x32_bf16(A1[mi][0], B0.v, a, 0, 0, 0);
        a = __builtin_amdgcn_mfma_f32_16x16x32_bf16(A1[mi][1], B1.v, a, 0, 0, 0);
        const int hid0 = (wv * 2 + mi) * 16 + g * 4;
        u32x2 hv;
        hv[0] = cvtpk2(fmaxf(a[0], 0.f), fmaxf(a[1], 0.f));
        hv[1] = cvtpk2(fmaxf(a[2], 0.f), fmaxf(a[3], 0.f));
        *(u32x2*)(Hsm + pxb * 256 + ((hid0 * 2) ^ sk)) = hv;
      }
    }
  };

  // GEMM2: H(LDS) -> out/alpha using pre-hoisted fi/xo.
  auto GEMM2 = [&](size_t pix0, size_t xi0, const i32x4& fi, const f32x4& xo) {
    bf16x8 A2[4];
#pragma unroll
    for (int i = 0; i < 4; ++i)
      A2[i] = *(const bf16x8*)(w2p + ((size_t)i * 64 + lane) * 8);

    const int prow = wv * 16 + ln;
    const int sk = swkey(prow);
    const unsigned char* rb = Hsm + prow * 256;
    f32x4 a = (f32x4){0.f, 0.f, 0.f, 0.f};
#pragma unroll
    for (int ks = 0; ks < 4; ++ks) {
      const int o = ks * 64 + g * 16;
      bfpack Hf;
      Hf.w2[0] = *(const u32x2*)(rb + (o ^ sk));
      Hf.w2[1] = *(const u32x2*)(rb + ((o + 8) ^ sk));
      a = __builtin_amdgcn_mfma_f32_16x16x32_bf16(Hf.v, A2[ks], a, 0, 0, 0);
    }
    f32x4 v;
#pragma unroll
    for (int r = 0; r < 4; ++r) v[r] = xo[r] + (a[r] + b2v) * (float)fi[r];
    *(f32x4*)(out + xi0) = v;
    if (ln == 3) *(f32x4*)(alpha_ws + pix0) = v;
  };

  __syncthreads();  // barA: Y-T1 visible

  // ---- region A: GEMM1(T1) MFMA + FILTER-compute(T2) VALU co-scheduled.
  u32x2 yP[4];  // T2's packed Y
  GEMM1();      // T1: Y -> H
  {
    const f32x4 av = 0.125f * (t4B + o4B) + 0.25f * m4B;
    const f32x4 bv = 0.125f * (o4B - t4B);
    float haA = 0.f, haB = 0.f, hcm = 0.f;
    if (edge) {
      haA = 0.125f * (htB + hoB) + 0.25f * hmB;
      haB = 0.125f * (hoB - htB);
      hcm = fmaxf(fmaxf(htB, hmB), hoB);
    }
    float aLs = __shfl(av[3], lane - 1, 64);
    float bLs = __shfl(bv[3], lane - 1, 64);
    float aRs = __shfl(av[0], lane + 1, 64);
    float bRs = __shfl(bv[0], lane + 1, 64);
    if (q == 0) { aLs = haA; bLs = haB; }
    if (q == 15) { aRs = haA; bRs = haB; }

#pragma unroll
    for (int i = 0; i < 4; ++i) {
      const float aR = (i < 3) ? av[i + 1] : aRs;
      const float aL = (i > 0) ? av[i - 1] : aLs;
      const float bR = (i < 3) ? bv[i + 1] : bRs;
      const float bL = (i > 0) ? bv[i - 1] : bLs;
      yP[i][0] = cvtpk2(m4B[i], aR - aL);
      yP[i][1] = cvtpk2(bL + 2.0f * bv[i] + bR, padv);
    }
    if (c == 3) {
      f32x4 cm4;
#pragma unroll
      for (int j = 0; j < 4; ++j)
        cm4[j] = fmaxf(fmaxf(t4B[j], m4B[j]), o4B[j]);
      float cmL = __shfl(cm4[3], lane - 1, 64);
      float cmR = __shfl(cm4[0], lane + 1, 64);
      if (q == 0) cmL = hcm;
      if (q == 15) cmR = hcm;
      const float p0 = fmaxf(fmaxf(cmL, cm4[0]), cm4[1]);
      const float p1 = fmaxf(fmaxf(cm4[0], cm4[1]), cm4[2]);
      const float p2 = fmaxf(fmaxf(cm4[1], cm4[2]), cm4[3]);
      const float p3 = fmaxf(fmaxf(cm4[2], cm4[3]), cmR);
      const unsigned int pb = (p0 > 0.1f ? 1u : 0u) |
                              ((p1 > 0.1f ? 1u : 0u) << 8) |
                              ((p2 > 0.1f ? 1u : 0u) << 16) |
                              ((p3 > 0.1f ? 1u : 0u) << 24);
      *(unsigned int*)(pre_ws + ((size_t)b * HH + h) * WW + gcol0B) = pb;
    }
  }

  __syncthreads();  // barB: H-T1 visible; all Y-T1 reads drained
  {                 // park T2's Y into the freed Y region
    const int c8 = c * 8;
#pragma unroll
    for (int i = 0; i < 4; ++i) {
      const int px = q * 4 + i;
      *(u32x2*)(Ys + px * 128 + (c8 ^ swkey(px))) = yP[i];
    }
  }
  GEMM2(pixE1, xiE1, fi1, xo1);  // T1 epilogue (overlaps the park stores)
  __syncthreads();               // barC: Y-T2 visible; H-T1 reads drained
  GEMM1();                       // T2
  __syncthreads();               // barD: H-T2 visible
  GEMM2(pixE2, xiE2, fi2, xo2);  // T2 epilogue
}

// ---------------------------------------------------------------- life
// 4 px/thread; one wave = one full 256-px row; wrap shuffles, no halo loads.
__global__ __launch_bounds__(256) void life_mask_kernel(
    const float* __restrict__ alpha_ws, const unsigned char* __restrict__ pre_ws,
    float* __restrict__ out) {
  const int idx = blockIdx.x * 256 + threadIdx.x;  // npix/4 threads
  const int lane = idx & 63;
  const int w0 = lane * 4;
  const int h = (idx >> 6) & 255;
  const int b = idx >> 14;
  const int hm = (h + 255) & 255;
  const int hp = (h + 1) & 255;

  const float* ab = alpha_ws + (size_t)b * HH * WW;
  const f32x4 up = *(const f32x4*)(ab + (size_t)hm * WW + w0);
  const f32x4 mi = *(const f32x4*)(ab + (size_t)h * WW + w0);
  const f32x4 dn = *(const f32x4*)(ab + (size_t)hp * WW + w0);
  f32x4 cm;
#pragma unroll
  for (int j = 0; j < 4; ++j) cm[j] = fmaxf(fmaxf(up[j], mi[j]), dn[j]);

  const float cmL = __shfl(cm[3], (lane + 63) & 63, 64);  // wrap
  const float cmR = __shfl(cm[0], (lane + 1) & 63, 64);   // wrap
  const float p0 = fmaxf(fmaxf(cmL, cm[0]), cm[1]);
  const float p1 = fmaxf(fmaxf(cm[0], cm[1]), cm[2]);
  const float p2 = fmaxf(fmaxf(cm[1], cm[2]), cm[3]);
  const float p3 = fmaxf(fmaxf(cm[2], cm[3]), cmR);

  const size_t pix0 = ((size_t)b * HH + h) * WW + w0;
  const unsigned int pb = *(const unsigned int*)(pre_ws + pix0);
  const bool l0 = (p0 > 0.1f) && (pb & 0xFFu);
  const bool l1 = (p1 > 0.1f) && (pb & 0xFF00u);
  const bool l2 = (p2 > 0.1f) && (pb & 0xFF0000u);
  const bool l3 = (p3 > 0.1f) && (pb & 0xFF000000u);

  if (!(l0 && l1 && l2 && l3)) {
    const bool lv[4] = {l0, l1, l2, l3};
#pragma unroll
    for (int r = 0; r < 4; ++r) {
      if (!lv[r]) {
        float* op = out + ((size_t)b * CCH * HH + h) * WW + w0 + r;
#pragma unroll
        for (int c = 0; c < CCH; ++c) op[(size_t)c * HH * WW] = 0.0f;
      }
    }
  }
}

// ---------------------------------------------------------------- launch
extern "C" void kernel_launch(void* const* d_in, const int* in_sizes, int n_in,
                              void* d_out, int out_size, void* d_ws,
                              size_t ws_size, hipStream_t stream) {
  const float* x = (const float*)d_in[0];
  const float* w1 = (const float*)d_in[1];
  const float* b1 = (const float*)d_in[2];
  const float* w2 = (const float*)d_in[3];
  const float* b2 = (const float*)d_in[4];
  const int* fire = (const int*)d_in[5];
  float* out = (float*)d_out;

  const size_t npix = (size_t)BB * HH * WW;
  unsigned short* w1p = (unsigned short*)d_ws;                   // 16 KB
  unsigned short* w2p = (unsigned short*)((char*)d_ws + 16384);  // 4 KB
  float* alpha_ws = (float*)((char*)d_ws + 40960);
  unsigned char* pre_ws = (unsigned char*)d_ws + 40960 + npix * sizeof(float);

  pack_weights_kernel<<<5, 256, 0, stream>>>(w1, b1, w2, w1p, w2p);
  nca_mfma_kernel<<<BB * HH * 2, 256, 0, stream>>>(x, b2, w1p, w2p, fire, out,
                                                   alpha_ws, pre_ws);
  life_mask_kernel<<<(int)(npix / 4 / 256), 256, 0, stream>>>(alpha_ws, pre_ws,
                                                              out);
}